// Round 2
// baseline (45073.697 us; speedup 1.0000x reference)
//
#include <hip/hip_runtime.h>
#include <hip/hip_bf16.h>

// Problem constants
#define S_LEN 512
#define BATCH 64
#define IDIM 1024
#define HDIM 1024
#define NG   4096              // 4*H
#define MROWS (S_LEN*BATCH)    // 32768
#define NWG  512               // scan workgroups

// ---------------------------------------------------------------------------
// Phase 1: xW[s,b,g] = sum_i x[s,b,i] * W_w[g,i] + W_b[g]   (unchanged)
// ---------------------------------------------------------------------------
__global__ __launch_bounds__(256) void xw_gemm(
    const float* __restrict__ X,            // [32768,1024]
    const float* __restrict__ Wg,           // [4096,1024]
    const float* __restrict__ Wb,           // [4096]
    float* __restrict__ out_f,              // [32768,4096] (if !use_bf)
    __hip_bfloat16* __restrict__ out_b,     // same, bf16 (if use_bf)
    int use_bf)
{
    __shared__ float As[16][128];   // [k][m]
    __shared__ float Bs[16][128];   // [k][n]

    const int tid = threadIdx.x;
    const int tx = tid & 15;        // n-tile
    const int ty = tid >> 4;        // m-tile
    const int m0 = blockIdx.y * 128;
    const int n0 = blockIdx.x * 128;

    float acc[8][8];
#pragma unroll
    for (int i = 0; i < 8; ++i)
#pragma unroll
        for (int j = 0; j < 8; ++j) acc[i][j] = 0.f;

    for (int k0 = 0; k0 < IDIM; k0 += 16) {
#pragma unroll
        for (int c = 0; c < 2; ++c) {
            int chunk = tid + c * 256;
            int row = chunk >> 2;
            int kq  = chunk & 3;
            float4 av = *(const float4*)&X [(size_t)(m0 + row) * IDIM + k0 + kq * 4];
            float4 bv = *(const float4*)&Wg[(size_t)(n0 + row) * IDIM + k0 + kq * 4];
            As[kq*4+0][row] = av.x; As[kq*4+1][row] = av.y;
            As[kq*4+2][row] = av.z; As[kq*4+3][row] = av.w;
            Bs[kq*4+0][row] = bv.x; Bs[kq*4+1][row] = bv.y;
            Bs[kq*4+2][row] = bv.z; Bs[kq*4+3][row] = bv.w;
        }
        __syncthreads();

#pragma unroll
        for (int kk = 0; kk < 16; ++kk) {
            float4 a0 = *(const float4*)&As[kk][ty*4];
            float4 a1 = *(const float4*)&As[kk][64 + ty*4];
            float4 b0 = *(const float4*)&Bs[kk][tx*4];
            float4 b1 = *(const float4*)&Bs[kk][64 + tx*4];
            float am[8] = {a0.x,a0.y,a0.z,a0.w,a1.x,a1.y,a1.z,a1.w};
            float bn[8] = {b0.x,b0.y,b0.z,b0.w,b1.x,b1.y,b1.z,b1.w};
#pragma unroll
            for (int i = 0; i < 8; ++i)
#pragma unroll
                for (int j = 0; j < 8; ++j) acc[i][j] += am[i] * bn[j];
        }
        __syncthreads();
    }

    float wb[8];
#pragma unroll
    for (int j = 0; j < 8; ++j) {
        int n = n0 + ((j < 4) ? (tx*4 + j) : (64 + tx*4 + j - 4));
        wb[j] = Wb[n];
    }
#pragma unroll
    for (int i = 0; i < 8; ++i) {
        int m = m0 + ((i < 4) ? (ty*4 + i) : (64 + ty*4 + i - 4));
        size_t base = (size_t)m * NG + n0;
        if (!use_bf) {
            float4 v0, v1;
            v0.x = acc[i][0]+wb[0]; v0.y = acc[i][1]+wb[1];
            v0.z = acc[i][2]+wb[2]; v0.w = acc[i][3]+wb[3];
            v1.x = acc[i][4]+wb[4]; v1.y = acc[i][5]+wb[5];
            v1.z = acc[i][6]+wb[6]; v1.w = acc[i][7]+wb[7];
            *(float4*)&out_f[base + tx*4]      = v0;
            *(float4*)&out_f[base + 64 + tx*4] = v1;
        } else {
#pragma unroll
            for (int j = 0; j < 8; ++j) {
                int nn = (j < 4) ? (tx*4 + j) : (64 + tx*4 + j - 4);
                out_b[base + nn] = __float2bfloat16(acc[i][j] + wb[j]);
            }
        }
    }
}

// ---------------------------------------------------------------------------
// Phase 2: persistent scan, BARRIER-FREE (tagged 4B slots, 4-gen ring).
// This round: depth-4 prefetch (static pr0..pr3), xW loads issued AFTER the
// h prologue (vmcnt retires in issue order — HBM xW loads before h loads
// would put ~900cy on round-0's wait), per-WG round rotation to decorrelate
// stale-tag polls at step boundaries, s_setprio(1) around the FMA cluster.
// ---------------------------------------------------------------------------
#define UT_OFF   0                        // 1024*8 = 8192 words
#define HBUF_OFF 8192                     // 4 waves * 1032 words = 4128
#define RED_OFF  (8192 + 4128)            // [4][8][66] = 2112 words
#define SMEM_WORDS (RED_OFF + 2112)       // 14432 words = 57,728 B

#define HSLOTS 65536                      // one generation: [1024 k][64 b]
#define NBUF   4

typedef unsigned long long u64;
typedef unsigned int u32;

__device__ __forceinline__ u64 h_ld2(const u32* p) {
    return __hip_atomic_load((const u64*)p, __ATOMIC_RELAXED,
                             __HIP_MEMORY_SCOPE_AGENT);
}
__device__ __forceinline__ void h_st1(u32* p, float v, u32 tag3) {
    union { float f; u32 u; } c; c.f = v;
    __hip_atomic_store(p, (c.u & ~7u) | tag3, __ATOMIC_RELAXED,
                       __HIP_MEMORY_SCOPE_AGENT);
}

// fill one depth slot (8 u64 = 16 tagged words) for logical round R
#define FILL(PR, R) {                                                        \
    const int _o = (((R) + rot) & 15) * 512;                                 \
    _Pragma("unroll")                                                        \
    for (int q = 0; q < 8; ++q)                                              \
        PR[q] = h_ld2(hsrc + gbase[q >> 1] + _o + (q & 1) * 2);              \
}

// one round: validate PR, extract, refill PR for R+4, stage to LDS, FMA
#define PHASE(PR, R) {                                                       \
    const int prnd = ((R) + rot) & 15;                                       \
    const int _off = prnd * 512;                                             \
    for (;;) {                                                               \
        u32 bad = 0;                                                         \
        _Pragma("unroll")                                                    \
        for (int q = 0; q < 8; ++q) {                                        \
            u64 s = PR[q];                                                   \
            bad |= (((u32)s ^ tagv) | ((u32)(s >> 32) ^ tagv)) & 7u;         \
        }                                                                    \
        if (!bad) break;                                                     \
        _Pragma("unroll")                                                    \
        for (int q = 0; q < 8; ++q) {                                        \
            u64 s = PR[q];                                                   \
            if (((((u32)s) ^ tagv) | (((u32)(s >> 32)) ^ tagv)) & 7u)        \
                PR[q] = h_ld2(hsrc + gbase[q >> 1] + _off + (q & 1) * 2);    \
        }                                                                    \
    }                                                                        \
    float vv[16];                                                            \
    _Pragma("unroll")                                                        \
    for (int q = 0; q < 8; ++q) {                                            \
        union { u32 u; float f; } lo, hi;                                    \
        lo.u = (u32)PR[q]; hi.u = (u32)(PR[q] >> 32);                        \
        vv[q*2] = lo.f; vv[q*2+1] = hi.f;                                    \
    }                                                                        \
    if ((R) < 12) FILL(PR, (R) + 4)                                          \
    _Pragma("unroll")                                                        \
    for (int j = 0; j < 4; ++j)                                              \
        *(float4*)(smem + ldsoff[j]) =                                       \
            make_float4(vv[j*4], vv[j*4+1], vv[j*4+2], vv[j*4+3]);           \
    const int kbase = kseg * 128 + prnd * 8;                                 \
    __builtin_amdgcn_s_setprio(1);                                           \
    _Pragma("unroll")                                                        \
    for (int kk = 0; kk < 8; ++kk) {                                         \
        float2 uv = *(const float2*)(ut + (kbase + kk) * 8 + 2*g);           \
        const float* hr = hb + kk * 64 + bg * 8;                             \
        float4 ha = *(const float4*)(hr);                                    \
        float4 hc = *(const float4*)(hr + 4);                                \
        acc0[0] += uv.x * ha.x;  acc0[1] += uv.x * ha.y;                     \
        acc0[2] += uv.x * ha.z;  acc0[3] += uv.x * ha.w;                     \
        acc0[4] += uv.x * hc.x;  acc0[5] += uv.x * hc.y;                     \
        acc0[6] += uv.x * hc.z;  acc0[7] += uv.x * hc.w;                     \
        acc1[0] += uv.y * ha.x;  acc1[1] += uv.y * ha.y;                     \
        acc1[2] += uv.y * ha.z;  acc1[3] += uv.y * ha.w;                     \
        acc1[4] += uv.y * hc.x;  acc1[5] += uv.y * hc.y;                     \
        acc1[6] += uv.y * hc.z;  acc1[7] += uv.y * hc.w;                     \
    }                                                                        \
    __builtin_amdgcn_s_setprio(0);                                           \
}

__global__ __launch_bounds__(256, 2) void lstm_scan(
    const float* __restrict__ xw_f,
    const __hip_bfloat16* __restrict__ xw_b,
    int use_bf,
    const float* __restrict__ Uw,     // [4096,1024]
    const float* __restrict__ h0,     // [64,1024]
    const float* __restrict__ c0,     // [64,1024]
    float* __restrict__ out,          // hidden_seq | h_t | c_t
    u32* __restrict__ h_scr)          // [4][1024][64] tagged fp32 slots
{
    __shared__ float smem[SMEM_WORDS];

    const int tid  = threadIdx.x;
    const int lane = tid & 63;
    const int w    = tid >> 6;          // wave 0..3
    const int hp   = (tid >> 5) & 1;    // half-wave -> kseg parity
    const int kseg = 2*w + hp;          // 0..7 (128 k each)
    const int g    = (tid >> 3) & 3;    // gate 0..3 (i,f,g,o)
    const int bg   = tid & 7;           // batch octet
    const int u0   = blockIdx.x * 2;    // this WG's 2 hidden units
    const int rot  = blockIdx.x & 15;   // per-WG round rotation

    // ---- one-time: stage U rows (transposed [k][r]) ----
#pragma unroll
    for (int r = 0; r < 8; ++r) {
        int q  = r >> 1;    // gate
        int uu = r & 1;     // unit
        const float4* grow = (const float4*)(Uw + (size_t)(q*HDIM + u0 + uu) * IDIM);
        float4 v = grow[tid];
        smem[UT_OFF + (tid*4+0)*8 + r] = v.x;
        smem[UT_OFF + (tid*4+1)*8 + r] = v.y;
        smem[UT_OFF + (tid*4+2)*8 + r] = v.z;
        smem[UT_OFF + (tid*4+3)*8 + r] = v.w;
    }

    // ---- one-time: transpose h0 into buffer 0 with tag 0 (128 slots/WG) ----
    if (tid < 128) {
        int slot = blockIdx.x * 128 + tid;      // 512*128 = 65536
        int b = slot & 63;
        int k = slot >> 6;
        h_st1(&h_scr[slot], h0[(size_t)b * HDIM + k], 0u);
    }

    // ---- one-time: c0 into registers ----
    const int eb = tid >> 1;    // batch (elementwise mapping, tid<128)
    const int eu = tid & 1;     // unit
    float creg = 0.f;
    if (tid < 128) creg = c0[(size_t)eb * HDIM + u0 + eu];

    // per-lane constant offsets (slot units)
    int gbase[4], ldsoff[4];
#pragma unroll
    for (int j = 0; j < 4; ++j) {
        int half = j >> 1, part = j & 1;
        gbase[j]  = (2*w + half) * 8192 + part * 256 + lane * 4;
        ldsoff[j] = HBUF_OFF + w * 1032 + half * 516 + part * 256 + lane * 4;
    }
    const float* hb = smem + HBUF_OFF + w * 1032 + hp * 516;
    const float* ut = smem + UT_OFF;

    __syncthreads();    // U staged in LDS

    for (int t = 0; t < S_LEN; ++t) {
        const u32* hsrc = h_scr + (size_t)(t & 3) * HSLOTS;
        const u32 tagv  = (u32)((t >> 2) & 7);

        float acc0[8], acc1[8];
#pragma unroll
        for (int j = 0; j < 8; ++j) { acc0[j] = 0.f; acc1[j] = 0.f; }

        // depth-4 prologue: h rounds 0..3 in flight FIRST (their waitcnt
        // must not be held back by slower HBM xW loads — in-order retire)
        u64 pr0[8], pr1[8], pr2[8], pr3[8];
        FILL(pr0, 0)
        FILL(pr1, 1)
        FILL(pr2, 2)
        FILL(pr3, 3)

        // xW prefetch (HBM; consumed only in the tail) — issued AFTER h
        float xf[4] = {0.f, 0.f, 0.f, 0.f};
        if (tid < 128) {
            size_t base = ((size_t)t * BATCH + eb) * NG + u0 + eu;
            if (!use_bf) {
#pragma unroll
                for (int q = 0; q < 4; ++q) xf[q] = xw_f[base + q*HDIM];
            } else {
#pragma unroll
                for (int q = 0; q < 4; ++q) xf[q] = __bfloat162float(xw_b[base + q*HDIM]);
            }
        }

        // 16 rounds, 4 per iteration (static prefetch-buffer indexing)
#pragma unroll 1
        for (int rb = 0; rb < 16; rb += 4) {
            PHASE(pr0, rb + 0)
            PHASE(pr1, rb + 1)
            PHASE(pr2, rb + 2)
            PHASE(pr3, rb + 3)
        }

        // reduce kseg pairs (lanes l <-> l^32 share (g,bg))
#pragma unroll
        for (int j = 0; j < 8; ++j) {
            acc0[j] += __shfl_xor(acc0[j], 32, 64);
            acc1[j] += __shfl_xor(acc1[j], 32, 64);
        }
        if (hp == 0) {
#pragma unroll
            for (int j = 0; j < 8; ++j) {
                smem[RED_OFF + (w*8 + g*2 + 0)*66 + bg*8 + j] = acc0[j];
                smem[RED_OFF + (w*8 + g*2 + 1)*66 + bg*8 + j] = acc1[j];
            }
        }
        __syncthreads();

        if (tid < 128) {
            float s[4];
#pragma unroll
            for (int q = 0; q < 4; ++q) {
                float v = xf[q];
#pragma unroll
                for (int ww = 0; ww < 4; ++ww)
                    v += smem[RED_OFF + (ww*8 + q*2 + eu)*66 + eb];
                s[q] = v;
            }
            float ig = 1.f / (1.f + expf(-s[0]));
            float fg = 1.f / (1.f + expf(-s[1]));
            float gv = tanhf(s[2]);
            float og = 1.f / (1.f + expf(-s[3]));
            creg = fg * creg + ig * gv;
            float hv = og * tanhf(creg);

            out[(size_t)t * 65536 + eb * HDIM + u0 + eu] = hv;
            h_st1(&h_scr[(size_t)((t + 1) & 3) * HSLOTS + (u0 + eu) * 64 + eb],
                  hv, (u32)(((t + 1) >> 2) & 7));
            if (t == S_LEN - 1) {
                out[33554432u + eb * HDIM + u0 + eu] = hv;    // h_t
                out[33619968u + eb * HDIM + u0 + eu] = creg;  // c_t
            }
        }

        // intra-WG only: protect RED buffer reuse next step
        __syncthreads();
    }
}

// ---------------------------------------------------------------------------
extern "C" void kernel_launch(void* const* d_in, const int* in_sizes, int n_in,
                              void* d_out, int out_size, void* d_ws, size_t ws_size,
                              hipStream_t stream) {
    const float* x   = (const float*)d_in[0];
    const float* h0  = (const float*)d_in[1];
    const float* c0  = (const float*)d_in[2];
    const float* Ww  = (const float*)d_in[3];
    const float* Wb  = (const float*)d_in[4];
    const float* Uw  = (const float*)d_in[5];
    float* out = (float*)d_out;

    const size_t xw_f32_bytes = (size_t)MROWS * NG * 4;        // 512 MB
    const size_t hscr_bytes   = (size_t)NBUF * HSLOTS * 4;     // 1 MB
    const int use_bf = (ws_size < xw_f32_bytes + hscr_bytes) ? 1 : 0;
    const size_t xw_bytes = use_bf ? (xw_f32_bytes / 2) : xw_f32_bytes;

    float* xw_f = (float*)d_ws;
    __hip_bfloat16* xw_b = (__hip_bfloat16*)d_ws;
    u32* h_scr = (u32*)((char*)d_ws + xw_bytes);

    // No memset needed: generation tags self-validate over workspace poison.

    // Phase 1: input projection GEMM
    xw_gemm<<<dim3(NG/128, MROWS/128), dim3(256), 0, stream>>>(
        x, Ww, Wb, xw_f, xw_b, use_bf);

    // Phase 2: persistent scan (barrier-free; tags carry all flow control).
    const float* xwf_c = xw_f;
    const __hip_bfloat16* xwb_c = xw_b;
    int ub = use_bf;
    void* args[] = { (void*)&xwf_c, (void*)&xwb_c, (void*)&ub,
                     (void*)&Uw, (void*)&h0, (void*)&c0,
                     (void*)&out, (void*)&h_scr };
    hipError_t err = hipLaunchCooperativeKernel((void*)lstm_scan, dim3(NWG),
                                                dim3(256), args, 0, stream);
    if (err != hipSuccess) {
        lstm_scan<<<dim3(NWG), dim3(256), 0, stream>>>(
            xwf_c, xwb_c, ub, Uw, h0, c0, out, h_scr);
    }
}

// Round 3
// 10477.695 us; speedup vs baseline: 4.3019x; 4.3019x over previous
//
#include <hip/hip_runtime.h>
#include <hip/hip_bf16.h>

// Problem constants
#define S_LEN 512
#define BATCH 64
#define IDIM 1024
#define HDIM 1024
#define NG   4096              // 4*H
#define MROWS (S_LEN*BATCH)    // 32768
#define NWG  256               // scan workgroups (4 units each)
#define NTHR 512               // threads per scan WG (8 waves)

// ---------------------------------------------------------------------------
// Phase 1: xW[s,b,g] = sum_i x[s,b,i] * W_w[g,i] + W_b[g]   (unchanged)
// ---------------------------------------------------------------------------
__global__ __launch_bounds__(256) void xw_gemm(
    const float* __restrict__ X,            // [32768,1024]
    const float* __restrict__ Wg,           // [4096,1024]
    const float* __restrict__ Wb,           // [4096]
    float* __restrict__ out_f,              // [32768,4096] (if !use_bf)
    __hip_bfloat16* __restrict__ out_b,     // same, bf16 (if use_bf)
    int use_bf)
{
    __shared__ float As[16][128];   // [k][m]
    __shared__ float Bs[16][128];   // [k][n]

    const int tid = threadIdx.x;
    const int tx = tid & 15;        // n-tile
    const int ty = tid >> 4;        // m-tile
    const int m0 = blockIdx.y * 128;
    const int n0 = blockIdx.x * 128;

    float acc[8][8];
#pragma unroll
    for (int i = 0; i < 8; ++i)
#pragma unroll
        for (int j = 0; j < 8; ++j) acc[i][j] = 0.f;

    for (int k0 = 0; k0 < IDIM; k0 += 16) {
#pragma unroll
        for (int c = 0; c < 2; ++c) {
            int chunk = tid + c * 256;
            int row = chunk >> 2;
            int kq  = chunk & 3;
            float4 av = *(const float4*)&X [(size_t)(m0 + row) * IDIM + k0 + kq * 4];
            float4 bv = *(const float4*)&Wg[(size_t)(n0 + row) * IDIM + k0 + kq * 4];
            As[kq*4+0][row] = av.x; As[kq*4+1][row] = av.y;
            As[kq*4+2][row] = av.z; As[kq*4+3][row] = av.w;
            Bs[kq*4+0][row] = bv.x; Bs[kq*4+1][row] = bv.y;
            Bs[kq*4+2][row] = bv.z; Bs[kq*4+3][row] = bv.w;
        }
        __syncthreads();

#pragma unroll
        for (int kk = 0; kk < 16; ++kk) {
            float4 a0 = *(const float4*)&As[kk][ty*4];
            float4 a1 = *(const float4*)&As[kk][64 + ty*4];
            float4 b0 = *(const float4*)&Bs[kk][tx*4];
            float4 b1 = *(const float4*)&Bs[kk][64 + tx*4];
            float am[8] = {a0.x,a0.y,a0.z,a0.w,a1.x,a1.y,a1.z,a1.w};
            float bn[8] = {b0.x,b0.y,b0.z,b0.w,b1.x,b1.y,b1.z,b1.w};
#pragma unroll
            for (int i = 0; i < 8; ++i)
#pragma unroll
                for (int j = 0; j < 8; ++j) acc[i][j] += am[i] * bn[j];
        }
        __syncthreads();
    }

    float wb[8];
#pragma unroll
    for (int j = 0; j < 8; ++j) {
        int n = n0 + ((j < 4) ? (tx*4 + j) : (64 + tx*4 + j - 4));
        wb[j] = Wb[n];
    }
#pragma unroll
    for (int i = 0; i < 8; ++i) {
        int m = m0 + ((i < 4) ? (ty*4 + i) : (64 + ty*4 + i - 4));
        size_t base = (size_t)m * NG + n0;
        if (!use_bf) {
            float4 v0, v1;
            v0.x = acc[i][0]+wb[0]; v0.y = acc[i][1]+wb[1];
            v0.z = acc[i][2]+wb[2]; v0.w = acc[i][3]+wb[3];
            v1.x = acc[i][4]+wb[4]; v1.y = acc[i][5]+wb[5];
            v1.z = acc[i][6]+wb[6]; v1.w = acc[i][7]+wb[7];
            *(float4*)&out_f[base + tx*4]      = v0;
            *(float4*)&out_f[base + 64 + tx*4] = v1;
        } else {
#pragma unroll
            for (int j = 0; j < 8; ++j) {
                int nn = (j < 4) ? (tx*4 + j) : (64 + tx*4 + j - 4);
                out_b[base + nn] = __float2bfloat16(acc[i][j] + wb[j]);
            }
        }
    }
}

// ---------------------------------------------------------------------------
// Phase 2: persistent scan, BARRIER-FREE (tagged 4B slots, 4-gen ring).
// Geometry change vs round 1: 256 WGs x 512 threads x 4 hidden units each.
// Halves the global h-broadcast volume (64 MB/step instead of 128 MB/step)
// while keeping per-lane FMA count (2048/step) and waves/CU (8) identical.
// Prefetch stays depth-2 (depth-4 spilled to scratch in round 2: VGPR 128,
// 129 GB HBM writes). Kept: xW loads AFTER h prologue (in-order vmcnt
// retire), per-WG round rotation, setprio around FMA cluster.
//
// Thread map (tid 0..511):
//   wave w = tid>>6, kseg = tid>>5 (16 ksegs x 64 k), ll = tid&31,
//   g = (tid>>3)&3 (gate), bg = tid&7 (batch octet).
// Per step: 8 rounds x 8 k; per lane per round: 16 h slots loaded (8 u64),
// staged to kseg-private LDS, then 8kk x 4units x 8batches = 256 FMA.
// ---------------------------------------------------------------------------
#define UT_OFF   0                        // 1024 k * 16 cols  = 16384 words
#define HBUF_OFF 16384                    // 16 ksegs * 520    =  8320 words
#define RED_OFF  (16384 + 8320)           // 128 rows * 66     =  8448 words
#define SMEM_WORDS (RED_OFF + 8448)       // 33152 words = 132,608 B (dynamic)

#define HSLOTS 65536                      // one generation: [1024 k][64 b]
#define NBUF   4

typedef unsigned long long u64;
typedef unsigned int u32;

__device__ __forceinline__ u64 h_ld2(const u32* p) {
    return __hip_atomic_load((const u64*)p, __ATOMIC_RELAXED,
                             __HIP_MEMORY_SCOPE_AGENT);
}
__device__ __forceinline__ void h_st1(u32* p, float v, u32 tag3) {
    union { float f; u32 u; } c; c.f = v;
    __hip_atomic_store(p, (c.u & ~7u) | tag3, __ATOMIC_RELAXED,
                       __HIP_MEMORY_SCOPE_AGENT);
}

// fill one depth slot (8 u64 = 16 tagged words) for logical round R
#define FILLR(PR, R) {                                                       \
    const int _o = (((R) + rot) & 7) * 512;                                  \
    _Pragma("unroll")                                                        \
    for (int q = 0; q < 8; ++q)                                              \
        PR[q] = h_ld2(hsrc + gbase[q >> 1] + _o + (q & 1) * 2);              \
}

// one round: validate PR, extract, refill PR for R+2, stage to LDS, FMA
#define PHASER(PR, R) {                                                      \
    const int prnd = ((R) + rot) & 7;                                        \
    const int _off = prnd * 512;                                             \
    for (;;) {                                                               \
        u32 bad = 0;                                                         \
        _Pragma("unroll")                                                    \
        for (int q = 0; q < 8; ++q) {                                        \
            u64 s = PR[q];                                                   \
            bad |= (((u32)s ^ tagv) | ((u32)(s >> 32) ^ tagv)) & 7u;         \
        }                                                                    \
        if (!bad) break;                                                     \
        _Pragma("unroll")                                                    \
        for (int q = 0; q < 8; ++q) {                                        \
            u64 s = PR[q];                                                   \
            if (((((u32)s) ^ tagv) | (((u32)(s >> 32)) ^ tagv)) & 7u)        \
                PR[q] = h_ld2(hsrc + gbase[q >> 1] + _off + (q & 1) * 2);    \
        }                                                                    \
    }                                                                        \
    float vv[16];                                                            \
    _Pragma("unroll")                                                        \
    for (int q = 0; q < 8; ++q) {                                            \
        union { u32 u; float f; } lo, hi;                                    \
        lo.u = (u32)PR[q]; hi.u = (u32)(PR[q] >> 32);                        \
        vv[q*2] = lo.f; vv[q*2+1] = hi.f;                                    \
    }                                                                        \
    if ((R) < 6) FILLR(PR, (R) + 2)                                          \
    _Pragma("unroll")                                                        \
    for (int j = 0; j < 4; ++j)                                              \
        *(float4*)(smem + ldsoff[j]) =                                       \
            make_float4(vv[j*4], vv[j*4+1], vv[j*4+2], vv[j*4+3]);           \
    const int kbase = kseg * 64 + prnd * 8;                                  \
    __builtin_amdgcn_s_setprio(1);                                           \
    _Pragma("unroll")                                                        \
    for (int kk = 0; kk < 8; ++kk) {                                         \
        float4 uv = *(const float4*)(ut + (kbase + kk) * 16 + g4);           \
        const float* hr = hb + kk * 64 + bg8;                                \
        float4 ha = *(const float4*)(hr);                                    \
        float4 hc = *(const float4*)(hr + 4);                                \
        acc0[0] += uv.x * ha.x;  acc0[1] += uv.x * ha.y;                     \
        acc0[2] += uv.x * ha.z;  acc0[3] += uv.x * ha.w;                     \
        acc0[4] += uv.x * hc.x;  acc0[5] += uv.x * hc.y;                     \
        acc0[6] += uv.x * hc.z;  acc0[7] += uv.x * hc.w;                     \
        acc1[0] += uv.y * ha.x;  acc1[1] += uv.y * ha.y;                     \
        acc1[2] += uv.y * ha.z;  acc1[3] += uv.y * ha.w;                     \
        acc1[4] += uv.y * hc.x;  acc1[5] += uv.y * hc.y;                     \
        acc1[6] += uv.y * hc.z;  acc1[7] += uv.y * hc.w;                     \
        acc2[0] += uv.z * ha.x;  acc2[1] += uv.z * ha.y;                     \
        acc2[2] += uv.z * ha.z;  acc2[3] += uv.z * ha.w;                     \
        acc2[4] += uv.z * hc.x;  acc2[5] += uv.z * hc.y;                     \
        acc2[6] += uv.z * hc.z;  acc2[7] += uv.z * hc.w;                     \
        acc3[0] += uv.w * ha.x;  acc3[1] += uv.w * ha.y;                     \
        acc3[2] += uv.w * ha.z;  acc3[3] += uv.w * ha.w;                     \
        acc3[4] += uv.w * hc.x;  acc3[5] += uv.w * hc.y;                     \
        acc3[6] += uv.w * hc.z;  acc3[7] += uv.w * hc.w;                     \
    }                                                                        \
    __builtin_amdgcn_s_setprio(0);                                           \
}

__global__ __launch_bounds__(NTHR, 2) void lstm_scan(
    const float* __restrict__ xw_f,
    const __hip_bfloat16* __restrict__ xw_b,
    int use_bf,
    const float* __restrict__ Uw,     // [4096,1024]
    const float* __restrict__ h0,     // [64,1024]
    const float* __restrict__ c0,     // [64,1024]
    float* __restrict__ out,          // hidden_seq | h_t | c_t
    u32* __restrict__ h_scr)          // [4][1024][64] tagged fp32 slots
{
    extern __shared__ float smem[];

    const int tid  = threadIdx.x;
    const int ll   = tid & 31;          // lane within half-wave
    const int kseg = tid >> 5;          // 0..15 (64 k each)
    const int hp   = kseg & 1;          // kseg parity within wave
    const int w    = tid >> 6;          // wave 0..7
    const int g    = (tid >> 3) & 3;    // gate 0..3 (i,f,g,o)
    const int bg   = tid & 7;           // batch octet
    const int g4   = g * 4;
    const int bg8  = bg * 8;
    const int u0   = blockIdx.x * 4;    // this WG's 4 hidden units
    const int rot  = blockIdx.x & 7;    // per-WG round rotation

    // ---- one-time: stage U rows, layout UT[k][g*4+u] ----
    {
        const int r  = tid >> 5;        // 16 (g,u) rows
        const int gg = r >> 2;
        const int uu = r & 3;
        const float* urow = Uw + (size_t)(gg * HDIM + u0 + uu) * IDIM;
#pragma unroll
        for (int c = 0; c < 8; ++c) {
            int k0 = c * 128 + ll * 4;
            float4 v = *(const float4*)(urow + k0);
            smem[UT_OFF + (k0+0)*16 + r] = v.x;
            smem[UT_OFF + (k0+1)*16 + r] = v.y;
            smem[UT_OFF + (k0+2)*16 + r] = v.z;
            smem[UT_OFF + (k0+3)*16 + r] = v.w;
        }
    }

    // ---- one-time: transpose h0 into buffer 0 with tag 0 (256 slots/WG) ----
    if (tid < 256) {
        int slot = blockIdx.x * 256 + tid;      // 256*256 = 65536
        int b = slot & 63;
        int k = slot >> 6;
        h_st1(&h_scr[slot], h0[(size_t)b * HDIM + k], 0u);
    }

    // ---- one-time: c0 into registers (tid<256: eb=tid>>2, euu=tid&3) ----
    const int eb  = tid >> 2;
    const int euu = tid & 3;
    float creg = 0.f;
    if (tid < 256) creg = c0[(size_t)eb * HDIM + u0 + euu];

    // per-lane constant offsets (slot units)
    int gbase[4], ldsoff[4];
#pragma unroll
    for (int j = 0; j < 4; ++j) {
        gbase[j]  = kseg * 4096 + j * 128 + ll * 4;
        ldsoff[j] = HBUF_OFF + kseg * 520 + j * 128 + ll * 4;
    }
    const float* hb = smem + HBUF_OFF + kseg * 520;
    const float* ut = smem + UT_OFF;

    __syncthreads();    // U staged in LDS

    for (int t = 0; t < S_LEN; ++t) {
        const u32* hsrc = h_scr + (size_t)(t & 3) * HSLOTS;
        const u32 tagv  = (u32)((t >> 2) & 7);

        float acc0[8], acc1[8], acc2[8], acc3[8];
#pragma unroll
        for (int j = 0; j < 8; ++j)
            { acc0[j] = 0.f; acc1[j] = 0.f; acc2[j] = 0.f; acc3[j] = 0.f; }

        // depth-2 prologue: h rounds 0,1 in flight FIRST (their waitcnt must
        // not be held back by slower HBM xW loads — in-order vmcnt retire)
        u64 pr0[8], pr1[8];
        FILLR(pr0, 0)
        FILLR(pr1, 1)

        // xW prefetch (HBM; consumed only in the tail) — issued AFTER h
        float xf[4] = {0.f, 0.f, 0.f, 0.f};
        if (tid < 256) {
            size_t base = ((size_t)t * BATCH + eb) * NG + u0 + euu;
            if (!use_bf) {
#pragma unroll
                for (int q = 0; q < 4; ++q) xf[q] = xw_f[base + q*HDIM];
            } else {
#pragma unroll
                for (int q = 0; q < 4; ++q) xf[q] = __bfloat162float(xw_b[base + q*HDIM]);
            }
        }

        // 8 rounds, 2 per iteration (static prefetch-buffer indexing)
#pragma unroll 1
        for (int rb = 0; rb < 8; rb += 2) {
            PHASER(pr0, rb + 0)
            PHASER(pr1, rb + 1)
        }

        // reduce kseg pairs (lanes l <-> l^32 share (g,bg))
#pragma unroll
        for (int j = 0; j < 8; ++j) {
            acc0[j] += __shfl_xor(acc0[j], 32, 64);
            acc1[j] += __shfl_xor(acc1[j], 32, 64);
            acc2[j] += __shfl_xor(acc2[j], 32, 64);
            acc3[j] += __shfl_xor(acc3[j], 32, 64);
        }
        if (hp == 0) {
#pragma unroll
            for (int j = 0; j < 8; ++j) {
                smem[RED_OFF + (w*16 + g4 + 0)*66 + bg8 + j] = acc0[j];
                smem[RED_OFF + (w*16 + g4 + 1)*66 + bg8 + j] = acc1[j];
                smem[RED_OFF + (w*16 + g4 + 2)*66 + bg8 + j] = acc2[j];
                smem[RED_OFF + (w*16 + g4 + 3)*66 + bg8 + j] = acc3[j];
            }
        }
        __syncthreads();

        if (tid < 256) {
            float s[4];
#pragma unroll
            for (int q = 0; q < 4; ++q) {
                float v = xf[q];
#pragma unroll
                for (int ww = 0; ww < 8; ++ww)
                    v += smem[RED_OFF + (ww*16 + q*4 + euu)*66 + eb];
                s[q] = v;
            }
            float ig = 1.f / (1.f + expf(-s[0]));
            float fg = 1.f / (1.f + expf(-s[1]));
            float gv = tanhf(s[2]);
            float og = 1.f / (1.f + expf(-s[3]));
            creg = fg * creg + ig * gv;
            float hv = og * tanhf(creg);

            out[(size_t)t * 65536 + eb * HDIM + u0 + euu] = hv;
            h_st1(&h_scr[(size_t)((t + 1) & 3) * HSLOTS + (u0 + euu) * 64 + eb],
                  hv, (u32)(((t + 1) >> 2) & 7));
            if (t == S_LEN - 1) {
                out[33554432u + eb * HDIM + u0 + euu] = hv;    // h_t
                out[33619968u + eb * HDIM + u0 + euu] = creg;  // c_t
            }
        }

        // intra-WG only: protect RED buffer reuse next step
        __syncthreads();
    }
}

// ---------------------------------------------------------------------------
extern "C" void kernel_launch(void* const* d_in, const int* in_sizes, int n_in,
                              void* d_out, int out_size, void* d_ws, size_t ws_size,
                              hipStream_t stream) {
    const float* x   = (const float*)d_in[0];
    const float* h0  = (const float*)d_in[1];
    const float* c0  = (const float*)d_in[2];
    const float* Ww  = (const float*)d_in[3];
    const float* Wb  = (const float*)d_in[4];
    const float* Uw  = (const float*)d_in[5];
    float* out = (float*)d_out;

    const size_t xw_f32_bytes = (size_t)MROWS * NG * 4;        // 512 MB
    const size_t hscr_bytes   = (size_t)NBUF * HSLOTS * 4;     // 1 MB
    const int use_bf = (ws_size < xw_f32_bytes + hscr_bytes) ? 1 : 0;
    const size_t xw_bytes = use_bf ? (xw_f32_bytes / 2) : xw_f32_bytes;

    float* xw_f = (float*)d_ws;
    __hip_bfloat16* xw_b = (__hip_bfloat16*)d_ws;
    u32* h_scr = (u32*)((char*)d_ws + xw_bytes);

    // No memset needed: generation tags self-validate over workspace poison.

    // Phase 1: input projection GEMM
    xw_gemm<<<dim3(NG/128, MROWS/128), dim3(256), 0, stream>>>(
        x, Ww, Wb, xw_f, xw_b, use_bf);

    // Phase 2: persistent scan. 132.6 KB LDS -> dynamic shared mem opt-in
    // (host-side attribute set; not a stream op, graph-capture-safe).
    const size_t smem_bytes = (size_t)SMEM_WORDS * 4;   // 132,608 B
    static int attr_done = 0;
    if (!attr_done) {
        hipFuncSetAttribute((const void*)lstm_scan,
                            hipFuncAttributeMaxDynamicSharedMemorySize,
                            (int)smem_bytes);
        attr_done = 1;
    }

    const float* xwf_c = xw_f;
    const __hip_bfloat16* xwb_c = xw_b;
    int ub = use_bf;
    void* args[] = { (void*)&xwf_c, (void*)&xwb_c, (void*)&ub,
                     (void*)&Uw, (void*)&h0, (void*)&c0,
                     (void*)&out, (void*)&h_scr };
    hipError_t err = hipLaunchCooperativeKernel((void*)lstm_scan, dim3(NWG),
                                                dim3(NTHR), args,
                                                (unsigned)smem_bytes, stream);
    if (err != hipSuccess) {
        lstm_scan<<<dim3(NWG), dim3(NTHR), smem_bytes, stream>>>(
            xwf_c, xwb_c, ub, Uw, h0, c0, out, h_scr);
    }
}